// Round 2
// 738.770 us; speedup vs baseline: 1.1797x; 1.1797x over previous
//
#include <hip/hip_runtime.h>

// SimplifiedAttention on MI355X (gfx950)
//   Qn = l2norm(q, dim=-1); Kn = l2norm(k, dim=-1)
//   W  = Qn @ Kn^T   [4, 4096, 4096]  (output 1)
//   O  = W  @ v      [4, 4096, 1024]  (output 0)
// R4: 256x256 8-phase GEMM (T2 XOR-swizzle + T3/T4 counted vmcnt + T5 setprio).
//     FIX vs R3: staggered per-wave quadrants — each wave's A footprint spans
//     both staged A-halves (MH selects half) and B footprint spans both B-halves
//     (NH selects half), so phase p only reads halves landed by the counted
//     vmcnt schedule (entry: A0,B0; end-p1: +B1; end-p2: +A1). R3 concentrated
//     wr=1/wc>=2 waves in the late-landing halves -> read-before-land -> NaN.

#define SEQ 4096
#define EMB 1024
#define NBATCH 4

typedef __attribute__((ext_vector_type(8))) __bf16 bf16x8;
typedef __attribute__((ext_vector_type(4))) float f32x4;
typedef const __attribute__((address_space(1))) void* gas_ptr;
typedef __attribute__((address_space(3))) void* las_ptr;

__device__ __forceinline__ void gld_lds16(const void* g, void* l) {
    // async global->LDS DMA, 16 B/lane. LDS dest is wave-uniform base + lane*16:
    // callers MUST pass lane-contiguous chunk indices within each wave.
    __builtin_amdgcn_global_load_lds((gas_ptr)g, (las_ptr)l, 16, 0, 0);
}

__device__ __forceinline__ unsigned short f2bf(float f) {
    unsigned int u = __builtin_bit_cast(unsigned int, f);
    u += 0x7FFFu + ((u >> 16) & 1u);
    return (unsigned short)(u >> 16);
}

__device__ __forceinline__ bf16x8 ld_bf16x8(const unsigned short* p) {
    int4 v = *(const int4*)p;  // ds_read_b128
    return __builtin_bit_cast(bf16x8, v);
}

// One block (256 threads) per row of 1024 floats: L2-normalize, store bf16.
__global__ __launch_bounds__(256) void norm_rows_kernel(const float* __restrict__ src,
                                                        unsigned short* __restrict__ dst) {
    int row = blockIdx.x;
    int t = threadIdx.x;
    float4 v = *(const float4*)(src + (size_t)row * EMB + t * 4);
    float ss = v.x * v.x + v.y * v.y + v.z * v.z + v.w * v.w;
#pragma unroll
    for (int off = 32; off > 0; off >>= 1) ss += __shfl_down(ss, off, 64);
    __shared__ float red[4];
    if ((t & 63) == 0) red[t >> 6] = ss;
    __syncthreads();
    float tot = red[0] + red[1] + red[2] + red[3];
    float scale = 1.0f / fmaxf(sqrtf(tot), 1e-12f);  // F.normalize eps
    ushort4 o;
    o.x = f2bf(v.x * scale);
    o.y = f2bf(v.y * scale);
    o.z = f2bf(v.z * scale);
    o.w = f2bf(v.w * scale);
    *(ushort4*)(dst + (size_t)row * EMB + t * 4) = o;
}

// V [b][j][d] fp32 -> Vt [b][d][j] bf16, 64x64 LDS tiles, coalesced both sides.
__global__ __launch_bounds__(256) void transpose_v_kernel(const float* __restrict__ v,
                                                          unsigned short* __restrict__ vt) {
    __shared__ __align__(16) unsigned short T[64][68];
    int b = blockIdx.z;
    int j0 = blockIdx.x * 64;
    int d0 = blockIdx.y * 64;
    const float* vb = v + (size_t)b * SEQ * EMB;
    unsigned short* vtb = vt + (size_t)b * (size_t)EMB * SEQ;
    int t = threadIdx.x;
#pragma unroll
    for (int i = 0; i < 4; i++) {
        int lin = t + i * 256;
        int j = lin >> 4;
        int dseg = lin & 15;
        float4 x = *(const float4*)(vb + (size_t)(j0 + j) * EMB + d0 + dseg * 4);
        ushort4 o;
        o.x = f2bf(x.x); o.y = f2bf(x.y); o.z = f2bf(x.z); o.w = f2bf(x.w);
        *(ushort4*)&T[j][dseg * 4] = o;
    }
    __syncthreads();
#pragma unroll
    for (int i = 0; i < 4; i++) {
        int lin = t + i * 256;
        int d = lin >> 4;
        int jseg = lin & 15;
        ushort4 o;
        o.x = T[jseg * 4 + 0][d];
        o.y = T[jseg * 4 + 1][d];
        o.z = T[jseg * 4 + 2][d];
        o.w = T[jseg * 4 + 3][d];
        *(ushort4*)(vtb + (size_t)(d0 + d) * SEQ + j0 + jseg * 4) = o;
    }
}

// ---------------------------------------------------------------------------
// 256x256 8-phase GEMM: C[m][n] = sum_k A[m][k] * B[n][k], A/B bf16 row-major
// over k. 512 threads = 8 waves (2 M x 4 N), BK=64 double-buffered.
// Staging halves land in order A0(rows 0-127), B0(0-127), B1(128-255),
// A1(128-255); per-wave quadrants staggered so phase p reads only landed halves.
// ---------------------------------------------------------------------------

#define BAR __builtin_amdgcn_s_barrier()
#define LGKM0 asm volatile("s_waitcnt lgkmcnt(0)" ::: "memory")
#define VMCNT4 asm volatile("s_waitcnt vmcnt(4)" ::: "memory")
#define VMCNT0 asm volatile("s_waitcnt vmcnt(0)" ::: "memory")

#define MFMA1(MI, NI, AF, BV) \
    acc[MI][NI] = __builtin_amdgcn_mfma_f32_16x16x32_bf16(AF, BV, acc[MI][NI], 0, 0, 0)

#define MFMA16(MH, NH, BF) do { \
    __builtin_amdgcn_s_setprio(1); \
    MFMA1((MH)*4+0, (NH)*2+0, af[0][0], BF[0][0]); \
    MFMA1((MH)*4+0, (NH)*2+1, af[0][0], BF[1][0]); \
    MFMA1((MH)*4+1, (NH)*2+0, af[1][0], BF[0][0]); \
    MFMA1((MH)*4+1, (NH)*2+1, af[1][0], BF[1][0]); \
    MFMA1((MH)*4+2, (NH)*2+0, af[2][0], BF[0][0]); \
    MFMA1((MH)*4+2, (NH)*2+1, af[2][0], BF[1][0]); \
    MFMA1((MH)*4+3, (NH)*2+0, af[3][0], BF[0][0]); \
    MFMA1((MH)*4+3, (NH)*2+1, af[3][0], BF[1][0]); \
    MFMA1((MH)*4+0, (NH)*2+0, af[0][1], BF[0][1]); \
    MFMA1((MH)*4+0, (NH)*2+1, af[0][1], BF[1][1]); \
    MFMA1((MH)*4+1, (NH)*2+0, af[1][1], BF[0][1]); \
    MFMA1((MH)*4+1, (NH)*2+1, af[1][1], BF[1][1]); \
    MFMA1((MH)*4+2, (NH)*2+0, af[2][1], BF[0][1]); \
    MFMA1((MH)*4+2, (NH)*2+1, af[2][1], BF[1][1]); \
    MFMA1((MH)*4+3, (NH)*2+0, af[3][1], BF[0][1]); \
    MFMA1((MH)*4+3, (NH)*2+1, af[3][1], BF[1][1]); \
    __builtin_amdgcn_s_setprio(0); \
} while (0)

// ds_read of an A quadrant-half (4 m-frags x 2 k-steps). STAGGERED: MH selects
// the staged A-half (rows MH*128 + wr*64 + 0..63) so MH=0 reads only A0 and
// MH=1 only A1. Swizzled chunk = kc ^ (row&7); row&7 == l16&7 since all other
// row terms are multiples of 8.
#define LD_A(BUF, MH) do { \
    const unsigned short (*Ac)[64] = As[BUF]; \
    int rb = (MH) * 128 + wr * 64 + l16; \
    af[0][0] = ld_bf16x8(&Ac[rb +  0][swz0]); af[0][1] = ld_bf16x8(&Ac[rb +  0][swz1]); \
    af[1][0] = ld_bf16x8(&Ac[rb + 16][swz0]); af[1][1] = ld_bf16x8(&Ac[rb + 16][swz1]); \
    af[2][0] = ld_bf16x8(&Ac[rb + 32][swz0]); af[2][1] = ld_bf16x8(&Ac[rb + 32][swz1]); \
    af[3][0] = ld_bf16x8(&Ac[rb + 48][swz0]); af[3][1] = ld_bf16x8(&Ac[rb + 48][swz1]); \
} while (0)

// NH selects the staged B-half (rows NH*128 + wc*32 + 0..31).
#define LD_B(BUF, NH, BF) do { \
    const unsigned short (*Bc)[64] = Bs[BUF]; \
    int rb = (NH) * 128 + wc * 32 + l16; \
    BF[0][0] = ld_bf16x8(&Bc[rb +  0][swz0]); BF[0][1] = ld_bf16x8(&Bc[rb +  0][swz1]); \
    BF[1][0] = ld_bf16x8(&Bc[rb + 16][swz0]); BF[1][1] = ld_bf16x8(&Bc[rb + 16][swz1]); \
} while (0)

// Stage one half-tile (128 rows x 64 cols bf16 = 1024 chunks of 16B) via DMA.
// LDS dest linear in chunk id c = tid + i*512; global src column pre-swizzled
// by cc ^ (row&7) so the ds_read-side XOR reads it back (involution, rule #21).
#define STAGE_A(NB, AH, KN) do { \
    gld_lds16(Ab + (AH) * aHalf + ro0 + (KN), (unsigned short*)As[NB] + (AH) * 8192 + lc0); \
    gld_lds16(Ab + (AH) * aHalf + ro1 + (KN), (unsigned short*)As[NB] + (AH) * 8192 + lc1); \
} while (0)

#define STAGE_B(NB, BH, KN) do { \
    gld_lds16(Bb + (BH) * bHalf + sb0 + (KN), (unsigned short*)Bs[NB] + (BH) * 8192 + lc0); \
    gld_lds16(Bb + (BH) * bHalf + sb1 + (KN), (unsigned short*)Bs[NB] + (BH) * 8192 + lc1); \
} while (0)

// One K-tile (BK=64) = 4 phases, one output quadrant each. Per-wave vmcnt
// bookkeeping (steady state; each STAGE = 2 loads, order A0,B0,B1,A1):
//   entry p1: outstanding {B1_i, A1_i}=4; A0_i,B0_i landed -> p1 reads (MH0,NH0)
//   p1: +A0_{i+1} (6); VMCNT4 lands B1_i   -> p2 reads (MH0,NH1)
//   p2: +B0_{i+1} (6); VMCNT4 lands A1_i   -> p3 reads (MH1,NH1)
//   p3: +B1_{i+1} (6); no wait             -> p4 register-only (MH1,NH0)
//   p4: +A1_{i+1} (8); VMCNT4 lands A0_{i+1},B0_{i+1} -> next tile p1 OK
// Each wait sits BEFORE the trailing barrier, so after the barrier ALL waves'
// DMA portions of the landed halves are visible.
#define KTILE(CB, NB, KN, DOSTAGE) do { \
    /* phase 1: quadrant (MH0, NH0) <- halves A0, B0 */ \
    LD_A(CB, 0); LD_B(CB, 0, b0); \
    if (DOSTAGE) STAGE_A(NB, 0, KN); \
    BAR; LGKM0; \
    MFMA16(0, 0, b0); \
    VMCNT4; BAR; \
    /* phase 2: quadrant (MH0, NH1) <- half B1 */ \
    LD_B(CB, 1, b1); \
    if (DOSTAGE) STAGE_B(NB, 0, KN); \
    BAR; LGKM0; \
    MFMA16(0, 1, b1); \
    VMCNT4; BAR; \
    /* phase 3: quadrant (MH1, NH1) <- half A1 */ \
    LD_A(CB, 1); \
    if (DOSTAGE) STAGE_B(NB, 1, KN); \
    BAR; LGKM0; \
    MFMA16(1, 1, b1); \
    BAR; \
    /* phase 4: quadrant (MH1, NH0) (register-only; b0 live since p1) */ \
    if (DOSTAGE) STAGE_A(NB, 1, KN); \
    BAR; LGKM0; \
    MFMA16(1, 0, b0); \
    VMCNT4; BAR; \
} while (0)

template <bool WBF16>
__global__ __launch_bounds__(512, 2) void gemm256_kernel(
    const unsigned short* __restrict__ A, const unsigned short* __restrict__ B,
    float* __restrict__ C, unsigned short* __restrict__ Cb16,
    int lda, int ldb, int ldc, int K,
    long long strideA, long long strideB, long long strideC) {
    // [2 buffers][256 rows][64 cols] bf16 each for A and B: 128 KiB total.
    __shared__ __align__(16) unsigned short As[2][256][64];
    __shared__ __align__(16) unsigned short Bs[2][256][64];

    int bz = blockIdx.z;
    int m0 = blockIdx.y * 256;
    int n0 = blockIdx.x * 256;
    const unsigned short* Ab = A + (size_t)bz * strideA + (size_t)m0 * lda;
    const unsigned short* Bb = B + (size_t)bz * strideB + (size_t)n0 * ldb;
    float* Cb = C + (size_t)bz * strideC;
    unsigned short* Cb16b = WBF16 ? Cb16 + (size_t)bz * strideC : nullptr;

    int tid = threadIdx.x;
    int wave = tid >> 6, lane = tid & 63;
    int wr = wave >> 2, wc = wave & 3;       // 2 x 4 wave grid
    int quad = lane >> 4, l16 = lane & 15;
    // ds_read swizzled chunk offsets (shorts) for k-chunk quad (ks=0) / quad+4 (ks=1)
    int swz0 = ((quad) ^ (l16 & 7)) * 8;
    int swz1 = ((quad + 4) ^ (l16 & 7)) * 8;

    // staging geometry: chunk c0 = tid, c1 = tid + 512; row = c>>3, col-chunk = c&7.
    // (c1&7 == c0&7 and (c1>>3)&7 == (c0>>3)&7, so one swizzled col offset serves both)
    int r0 = tid >> 3;
    int cs0 = ((tid & 7) ^ (r0 & 7)) * 8;
    const int aHalf = 128 * lda, bHalf = 128 * ldb;
    int ro0 = r0 * lda + cs0;
    int ro1 = (r0 + 64) * lda + cs0;
    int sb0 = r0 * ldb + cs0;
    int sb1 = (r0 + 64) * ldb + cs0;
    unsigned lc0 = (unsigned)(tid * 8);           // LDS short-offset of chunk c0
    unsigned lc1 = (unsigned)(tid * 8 + 4096);    // chunk c1

    f32x4 acc[8][4] = {};
    bf16x8 af[4][2], b0[2][2], b1[2][2];

    const int NT = K >> 6;  // K-tiles of 64; NT is even and >= 4 for our shapes

    // prologue: stage tile 0 into buf0 in landing order; wait for A0,B0.
    STAGE_A(0, 0, 0); STAGE_B(0, 0, 0); STAGE_B(0, 1, 0); STAGE_A(0, 1, 0);
    VMCNT4; BAR;

    for (int i = 0; i < (NT >> 1) - 1; ++i) {
        KTILE(0, 1, ((2 * i + 1) << 6), 1);
        KTILE(1, 0, ((2 * i + 2) << 6), 1);
    }
    KTILE(0, 1, ((NT - 1) << 6), 1);  // tile NT-2, stages tile NT-1 into buf1
    VMCNT0; BAR;                      // epilogue drain: last tile fully landed
    KTILE(1, 0, 0, 0);                // tile NT-1, no staging

    // C/D layout (m89/m91 verified): col = lane&15, row = quad*4 + reg.
    // Staggered mapping: MI=(MH*4+mt) -> row MH*128 + wr*64 + mt*16;
    //                    NI=(NH*2+s)  -> col NH*128 + wc*32 + s*16.
#pragma unroll
    for (int mt8 = 0; mt8 < 8; ++mt8) {
        int row = m0 + (mt8 >> 2) * 128 + wr * 64 + (mt8 & 3) * 16 + quad * 4;
#pragma unroll
        for (int nt4 = 0; nt4 < 4; ++nt4) {
            int col = n0 + (nt4 >> 1) * 128 + wc * 32 + (nt4 & 1) * 16 + l16;
#pragma unroll
            for (int r = 0; r < 4; ++r) {
                float val = acc[mt8][nt4][r];
                Cb[(size_t)(row + r) * ldc + col] = val;
                if (WBF16) Cb16b[(size_t)(row + r) * ldc + col] = f2bf(val);
            }
        }
    }
}

// ---------------------------------------------------------------------------
// Fallback 128x128 kernel (ws-too-small path) — unchanged, known-correct.
// ---------------------------------------------------------------------------
template <int AMODE, bool WBF16>
__global__ __launch_bounds__(256) void gemm_tile_kernel(
    const void* __restrict__ Av, const unsigned short* __restrict__ B,
    float* __restrict__ C, unsigned short* __restrict__ Cb16,
    int lda, int ldb, int ldc, int K,
    long long strideA, long long strideB, long long strideC) {
    __shared__ __align__(16) unsigned short Asl[128][32];
    __shared__ __align__(16) unsigned short Bsl[128][32];

    int b = blockIdx.z;
    int m0 = blockIdx.y * 128;
    int n0 = blockIdx.x * 128;
    const unsigned short* Ab = nullptr;
    const float* Af = nullptr;
    if constexpr (AMODE == 1)
        Af = (const float*)Av + (size_t)b * strideA;
    else
        Ab = (const unsigned short*)Av + (size_t)b * strideA;
    const unsigned short* Bb = B + (size_t)b * strideB;
    float* Cb = C + (size_t)b * strideC;
    unsigned short* Cb16b = WBF16 ? Cb16 + (size_t)b * strideC : nullptr;

    int tid = threadIdx.x;
    int wave = tid >> 6, lane = tid & 63;
    int wr = wave >> 1, wc = wave & 1;
    int quad = lane >> 4, l16 = lane & 15;

    f32x4 acc[4][4] = {};

    for (int k0 = 0; k0 < K; k0 += 32) {
        __syncthreads();
        if constexpr (AMODE == 0) {
#pragma unroll
            for (int i = 0; i < 2; i++) {
                int c = tid + i * 256;
                int row = c >> 2, seg = c & 3;
                gld_lds16(Ab + (size_t)(m0 + row) * lda + k0 + seg * 8,
                          (unsigned short*)Asl + c * 8);
            }
        } else {
#pragma unroll
            for (int i = 0; i < 4; i++) {
                int lin = tid + i * 256;
                int row = lin >> 3;
                int seg = lin & 7;
                float4 x = *(const float4*)(Af + (size_t)(m0 + row) * lda + k0 + seg * 4);
                ushort4 o;
                o.x = f2bf(x.x); o.y = f2bf(x.y); o.z = f2bf(x.z); o.w = f2bf(x.w);
                *(ushort4*)&Asl[row][seg * 4] = o;
            }
        }
#pragma unroll
        for (int i = 0; i < 2; i++) {
            int c = tid + i * 256;
            int row = c >> 2, seg = c & 3;
            gld_lds16(Bb + (size_t)(n0 + row) * ldb + k0 + seg * 8,
                      (unsigned short*)Bsl + c * 8);
        }
        __syncthreads();

        bf16x8 afr[4], bfr[4];
#pragma unroll
        for (int mt = 0; mt < 4; mt++)
            afr[mt] = ld_bf16x8(&Asl[wr * 64 + mt * 16 + l16][quad * 8]);
#pragma unroll
        for (int nt = 0; nt < 4; nt++)
            bfr[nt] = ld_bf16x8(&Bsl[wc * 64 + nt * 16 + l16][quad * 8]);
#pragma unroll
        for (int mt = 0; mt < 4; mt++)
#pragma unroll
            for (int nt = 0; nt < 4; nt++)
                acc[mt][nt] = __builtin_amdgcn_mfma_f32_16x16x32_bf16(
                    afr[mt], bfr[nt], acc[mt][nt], 0, 0, 0);
    }

#pragma unroll
    for (int mt = 0; mt < 4; mt++) {
#pragma unroll
        for (int nt = 0; nt < 4; nt++) {
            int row = m0 + wr * 64 + mt * 16 + quad * 4;
            int col = n0 + wc * 64 + nt * 16 + l16;
#pragma unroll
            for (int r = 0; r < 4; r++) {
                float val = acc[mt][nt][r];
                Cb[(size_t)(row + r) * ldc + col] = val;
                if constexpr (WBF16)
                    Cb16b[(size_t)(row + r) * ldc + col] = f2bf(val);
            }
        }
    }
}

extern "C" void kernel_launch(void* const* d_in, const int* in_sizes, int n_in,
                              void* d_out, int out_size, void* d_ws, size_t ws_size,
                              hipStream_t stream) {
    const float* q = (const float*)d_in[0];
    const float* k = (const float*)d_in[1];
    const float* v = (const float*)d_in[2];

    const size_t elems = (size_t)NBATCH * SEQ * EMB;   // 16,777,216
    const size_t welems = (size_t)NBATCH * SEQ * SEQ;  // 67,108,864
    unsigned short* Qn = (unsigned short*)d_ws;        // 33.5 MB
    unsigned short* Kn = Qn + elems;                   // 33.5 MB
    unsigned short* Vt = Kn + elems;                   // 33.5 MB
    unsigned short* Wb = Vt + elems;                   // 134.2 MB (bf16 copy of W)
    const size_t ws_needed = (3 * elems + welems) * sizeof(unsigned short);
    const bool fast = ws_size >= ws_needed;

    float* O = (float*)d_out;   // [4,4096,1024]
    float* W = O + elems;       // [4,4096,4096]

    norm_rows_kernel<<<NBATCH * SEQ, 256, 0, stream>>>(q, Qn);
    norm_rows_kernel<<<NBATCH * SEQ, 256, 0, stream>>>(k, Kn);
    transpose_v_kernel<<<dim3(SEQ / 64, EMB / 64, NBATCH), 256, 0, stream>>>(v, Vt);

    if (fast) {
        // GEMM1: W[i][j] = sum_d Qn[i][d] Kn[j][d]   (M=N=4096, K=1024)
        gemm256_kernel<true><<<dim3(SEQ / 256, SEQ / 256, NBATCH), 512, 0, stream>>>(
            Qn, Kn, W, Wb, EMB, EMB, SEQ, EMB,
            (long long)SEQ * EMB, (long long)SEQ * EMB, (long long)SEQ * SEQ);
        // GEMM2: O[i][d] = sum_j Wb[i][j] Vt[d][j]  (M=4096, N=1024, K=4096)
        gemm256_kernel<false><<<dim3(EMB / 256, SEQ / 256, NBATCH), 512, 0, stream>>>(
            Wb, Vt, O, nullptr, SEQ, SEQ, EMB, SEQ,
            (long long)SEQ * SEQ, (long long)EMB * SEQ, (long long)SEQ * EMB);
    } else {
        gemm_tile_kernel<0, false><<<dim3(SEQ / 128, SEQ / 128, NBATCH), 256, 0, stream>>>(
            Qn, Kn, W, nullptr, EMB, EMB, SEQ, EMB,
            (long long)SEQ * EMB, (long long)SEQ * EMB, (long long)SEQ * SEQ);
        gemm_tile_kernel<1, false><<<dim3(EMB / 128, SEQ / 128, NBATCH), 256, 0, stream>>>(
            W, Vt, O, nullptr, SEQ, SEQ, EMB, SEQ,
            (long long)SEQ * SEQ, (long long)EMB * SEQ, (long long)SEQ * EMB);
    }
}